// Round 8
// baseline (744.095 us; speedup 1.0000x reference)
//
#include <hip/hip_runtime.h>
#include <hip/hip_bf16.h>

#define B_ 8
#define G_ 256
#define N_ 1024
#define P_ 4
#define F_ 256
#define KHOP 4
#define KG_ 1024
#define NBLK 512

typedef unsigned short ushort_t;
typedef __bf16 bf16x8 __attribute__((ext_vector_type(8)));
typedef unsigned short u16x8 __attribute__((ext_vector_type(8)));
typedef float f32x4 __attribute__((ext_vector_type(4)));

__device__ __forceinline__ unsigned short f2bf(float f) {
  union { float fl; unsigned int i; } v; v.fl = f;
  return (unsigned short)((v.i + 0x7fffu + ((v.i >> 16) & 1u)) >> 16);
}

__device__ __forceinline__ void gload_lds16(const ushort_t* g, ushort_t* l) {
  __builtin_amdgcn_global_load_lds(
      (const __attribute__((address_space(1))) void*)g,
      (__attribute__((address_space(3))) void*)l, 16, 0, 0);
}

// Device-scope grid barrier: monotone counter, one arrival per block.
// Counter lives in d_ws, zeroed by hipMemsetAsync before launch.
__device__ __forceinline__ void gridbar(unsigned* bar, unsigned target) {
  __syncthreads();
  if (threadIdx.x == 0) {
    __threadfence();
    __hip_atomic_fetch_add(bar, 1u, __ATOMIC_ACQ_REL, __HIP_MEMORY_SCOPE_AGENT);
    while (__hip_atomic_load(bar, __ATOMIC_ACQUIRE, __HIP_MEMORY_SCOPE_AGENT) < target) {
      __builtin_amdgcn_s_sleep(2);
    }
  }
  __syncthreads();
}

// ---------------------------------------------------------------------------
// P1a: e1/e2 for one (bp, n-chunk) job.  job in [0,128).
__device__ void prep_e(int job, const float* __restrict__ x,
                       const float* __restrict__ mixer, const float* __restrict__ weight,
                       const float* __restrict__ wb, float* __restrict__ e1,
                       float* __restrict__ e2, char* smem) {
  float* s1 = (float*)smem;            // [256]
  float* s2 = (float*)(smem + 1024);   // [256]
  float* cred = (float*)(smem + 2048); // [2][4]
  int t = threadIdx.x;
  int bp = job >> 2;
  int nc = job & 3;
  int b = bp >> 2, p = bp & (P_ - 1);
  int n = nc * 256 + t;
  float acc1 = 0.f, acc2 = 0.f;
  const float* wp = weight + (size_t)p * F_ * G_ + t;
  const float* mp = mixer + p * 2 * F_;
  for (int f = 0; f < F_; ++f) {
    float wv = wp[(size_t)f * G_];
    acc1 = fmaf(mp[f], wv, acc1);
    acc2 = fmaf(mp[F_ + f], wv, acc2);
  }
  __syncthreads();
  s1[t] = acc1;
  s2[t] = acc2;
  float c1p = mp[t] * wb[p * F_ + t];
  float c2p = mp[F_ + t] * wb[p * F_ + t];
#pragma unroll
  for (int mask = 1; mask < 64; mask <<= 1) {
    c1p += __shfl_xor(c1p, mask, 64);
    c2p += __shfl_xor(c2p, mask, 64);
  }
  if ((t & 63) == 0) {
    cred[t >> 6] = c1p;
    cred[4 + (t >> 6)] = c2p;
  }
  __syncthreads();
  float c1 = cred[0] + cred[1] + cred[2] + cred[3];
  float c2 = cred[4] + cred[5] + cred[6] + cred[7];
  const float* xb = x + (size_t)b * G_ * N_ + n;
  float a1 = 0.f, a2 = 0.f;
#pragma unroll 8
  for (int g = 0; g < G_; ++g) {
    float xv = xb[(size_t)g * N_];
    a1 = fmaf(s1[g], xv, a1);
    a2 = fmaf(s2[g], xv, a2);
  }
  e1[(size_t)bp * N_ + n] = c1 + a1;
  e2[(size_t)bp * N_ + n] = c2 + a2;
}

// ---------------------------------------------------------------------------
// P1b: filterWeight fp32->bf16, 1024 elems per job.
__device__ void prep_cast(int job, const float* __restrict__ fw,
                          ushort_t* __restrict__ fwbf) {
  int i = job * 1024 + threadIdx.x * 4;
  float4 v = *(const float4*)&fw[i];
  ushort4 o;
  o.x = f2bf(v.x); o.y = f2bf(v.y); o.z = f2bf(v.z); o.w = f2bf(v.w);
  *(ushort4*)&fwbf[i] = o;
}

// ---------------------------------------------------------------------------
// P1c: xT[b][n][g] = bf16(x[b][g][n]), one 64x64 tile per job (512 jobs).
__device__ void prep_xT(int job, const float* __restrict__ x,
                        ushort_t* __restrict__ xT, char* smem) {
  ushort_t* tile = (ushort_t*)smem;   // [64][66]
  int n0 = (job & 15) * 64;
  int g0 = ((job >> 4) & 3) * 64;
  int b = job >> 6;
  int t = threadIdx.x;
  int rr = t >> 4, cc = (t & 15) * 4;
  __syncthreads();
#pragma unroll
  for (int ps = 0; ps < 4; ++ps) {
    float4 v = *(const float4*)&x[((size_t)b * G_ + g0 + ps * 16 + rr) * N_ + n0 + cc];
    tile[(ps * 16 + rr) * 66 + cc] = f2bf(v.x);
    tile[(ps * 16 + rr) * 66 + cc + 1] = f2bf(v.y);
    tile[(ps * 16 + rr) * 66 + cc + 2] = f2bf(v.z);
    tile[(ps * 16 + rr) * 66 + cc + 3] = f2bf(v.w);
  }
  __syncthreads();
#pragma unroll
  for (int ps = 0; ps < 4; ++ps) {
    int nl = ps * 16 + rr;
    int gl = cc;
    ushort4 o;
    o.x = tile[gl * 66 + nl];
    o.y = tile[(gl + 1) * 66 + nl];
    o.z = tile[(gl + 2) * 66 + nl];
    o.w = tile[(gl + 3) * 66 + nl];
    *(ushort4*)&xT[((size_t)b * N_ + n0 + nl) * G_ + g0 + gl] = o;
  }
}

// ---------------------------------------------------------------------------
// P2: attention, UNNORMALIZED. One call per (bp, 64-i-tile, 256-j-tile).
// E[i,j] = m ? exp(lrelu(e1[j]+e2[i])) : 0 into an LDS tile stored
// TRANSPOSED [j][i]; row sums atomically into sumb; dump via vector LDS
// reads + coalesced 16B stores. Normalization (1/rowsum) applied in GEMM
// epilogues (algebra: xk . aij = (xk (.) inv) . E).
__device__ void att_body(int bp, int i0, int jt, const float* __restrict__ e1,
                         const float* __restrict__ e2, const float* __restrict__ S,
                         ushort_t* __restrict__ expT, float* __restrict__ sumb,
                         char* smem) {
  ushort_t* tile = (ushort_t*)smem;            // [256][72]
  float* se1 = (float*)(smem + 36864);         // [256]
  float* se2 = (float*)(smem + 36864 + 1024);  // [64]
  int b = bp >> 2;
  int j0 = jt * 256;
  int t = threadIdx.x;
  int rr = t >> 4;
  int cc4 = t & 15;
  int cc = cc4 * 4;

  se1[t] = e1[(size_t)bp * N_ + j0 + t];
  if (t < 64) se2[t] = e2[(size_t)bp * N_ + i0 + t];
  __syncthreads();

  const float* Sb = S + (size_t)b * N_ * N_;
  float re2[4];
#pragma unroll
  for (int ps = 0; ps < 4; ++ps) re2[ps] = se2[ps * 16 + rr];
  float psum[4] = {0.f, 0.f, 0.f, 0.f};
#pragma unroll
  for (int js = 0; js < 4; ++js) {
    float4 e1q = *(float4*)&se1[js * 64 + cc];
    float e1v[4] = {e1q.x, e1q.y, e1q.z, e1q.w};
#pragma unroll
    for (int ps = 0; ps < 4; ++ps) {
      int il = ps * 16 + rr;
      float4 s4 = *(const float4*)&Sb[(size_t)(i0 + il) * N_ + j0 + js * 64 + cc];
      float sv[4] = {s4.x, s4.y, s4.z, s4.w};
#pragma unroll
      for (int s = 0; s < 4; ++s) {
        float v = e1v[s] + re2[ps];
        float l = v >= 0.f ? v : 0.2f * v;
        bool m = fabsf(sv[s]) > 1e-9f;
        float e = m ? __expf(l) : 0.f;
        psum[ps] += e;
        tile[(js * 64 + cc + s) * 72 + il] = f2bf(e);
      }
    }
  }
#pragma unroll
  for (int mask = 1; mask < 16; mask <<= 1) {
#pragma unroll
    for (int ps = 0; ps < 4; ++ps) psum[ps] += __shfl_xor(psum[ps], mask, 64);
  }
  if (cc4 == 0) {
#pragma unroll
    for (int ps = 0; ps < 4; ++ps)
      atomicAdd(&sumb[(size_t)bp * N_ + i0 + ps * 16 + rr], psum[ps]);
  }
  __syncthreads();
  ushort_t* Tb = expT + (size_t)bp * N_ * N_;
  int jl0 = t >> 3;
  int ig = (t & 7) * 8;
#pragma unroll
  for (int pass = 0; pass < 8; ++pass) {
    int jl = pass * 32 + jl0;
    u16x8 v = *(const u16x8*)&tile[jl * 72 + ig];
    *(u16x8*)&Tb[(size_t)(j0 + jl) * N_ + i0 + ig] = v;
  }
}

// ---------------------------------------------------------------------------
// Horner step GEMM (NT, MFMA bf16, 128x128 tile, 4 waves, BK=64,
// 2-barrier rhythm). Work decoded from block id L as (x=8, y=2, z=32).
//   D[f,n] = [sum_m Aprev[bp][f][m] * expT[bp][n][m]]   (if has_prev)
//          +  sum_g fwbf[p][f][kslice*256+g] * xT[b][n][g]
//   last: out_f32 = lrelu(D + bias[f]);  else out_bf16 = bf16(D / sumb[n]).
__device__ void gemm_body(int L, const ushort_t* __restrict__ Aprev,
                          const ushort_t* __restrict__ Bt,
                          const ushort_t* __restrict__ fwbf,
                          const ushort_t* __restrict__ xT,
                          const float* __restrict__ bias,
                          const float* __restrict__ sumb,
                          ushort_t* __restrict__ outb, float* __restrict__ outf,
                          int kslice, int has_prev, int last, char* smem) {
  ushort_t* As = (ushort_t*)smem;            // [2][4096]
  ushort_t* Bs = (ushort_t*)(smem + 16384);  // [2][4096]
  int bp = L >> 4;
  int p = bp & (P_ - 1), b = bp >> 2;
  int n0 = (L & 7) * 128, m0 = ((L >> 3) & 1) * 128;
  int t = threadIdx.x;
  int lane = t & 63;
  int w = t >> 6;
  int wm = w >> 1, wn = w & 1;
  int lr = lane & 15, quad = lane >> 4;
  int rowL = t >> 2;
  int colL = (t & 3) * 8;
  int ldsoff = (t & ~63) * 8;

  const ushort_t* A1 = Aprev + (size_t)bp * (F_ * N_) + (size_t)(m0 + rowL) * N_ + colL;
  const ushort_t* B1 = Bt + (size_t)bp * N_ * N_ + (size_t)(n0 + rowL) * N_ + colL;
  const ushort_t* A2 = fwbf + (size_t)p * (F_ * KG_) + (size_t)(m0 + rowL) * KG_ +
                       kslice * G_ + colL;
  const ushort_t* B2 = xT + (size_t)b * (N_ * G_) + (size_t)(n0 + rowL) * G_ + colL;

  f32x4 acc[4][4] = {};

  if (has_prev) {
    for (int kt = 0; kt < N_; kt += 64) {
      __syncthreads();
      gload_lds16(A1 + kt, &As[ldsoff]);
      gload_lds16(A1 + (size_t)64 * N_ + kt, &As[2048 + ldsoff]);
      gload_lds16(A1 + kt + 32, &As[4096 + ldsoff]);
      gload_lds16(A1 + (size_t)64 * N_ + kt + 32, &As[4096 + 2048 + ldsoff]);
      gload_lds16(B1 + kt, &Bs[ldsoff]);
      gload_lds16(B1 + (size_t)64 * N_ + kt, &Bs[2048 + ldsoff]);
      gload_lds16(B1 + kt + 32, &Bs[4096 + ldsoff]);
      gload_lds16(B1 + (size_t)64 * N_ + kt + 32, &Bs[4096 + 2048 + ldsoff]);
      __syncthreads();
#pragma unroll
      for (int c = 0; c < 2; ++c) {
        bf16x8 af[4], bfr[4];
#pragma unroll
        for (int mi = 0; mi < 4; ++mi)
          af[mi] = __builtin_bit_cast(bf16x8,
              *(const u16x8*)&As[c * 4096 + (wm * 64 + mi * 16 + lr) * 32 + quad * 8]);
#pragma unroll
        for (int ni = 0; ni < 4; ++ni)
          bfr[ni] = __builtin_bit_cast(bf16x8,
              *(const u16x8*)&Bs[c * 4096 + (wn * 64 + ni * 16 + lr) * 32 + quad * 8]);
#pragma unroll
        for (int mi = 0; mi < 4; ++mi)
#pragma unroll
          for (int ni = 0; ni < 4; ++ni)
            acc[mi][ni] = __builtin_amdgcn_mfma_f32_16x16x32_bf16(af[mi], bfr[ni], acc[mi][ni], 0, 0, 0);
      }
    }
  }
  for (int gt = 0; gt < G_; gt += 64) {
    __syncthreads();
    gload_lds16(A2 + gt, &As[ldsoff]);
    gload_lds16(A2 + (size_t)64 * KG_ + gt, &As[2048 + ldsoff]);
    gload_lds16(A2 + gt + 32, &As[4096 + ldsoff]);
    gload_lds16(A2 + (size_t)64 * KG_ + gt + 32, &As[4096 + 2048 + ldsoff]);
    gload_lds16(B2 + gt, &Bs[ldsoff]);
    gload_lds16(B2 + (size_t)64 * G_ + gt, &Bs[2048 + ldsoff]);
    gload_lds16(B2 + gt + 32, &Bs[4096 + ldsoff]);
    gload_lds16(B2 + (size_t)64 * G_ + gt + 32, &Bs[4096 + 2048 + ldsoff]);
    __syncthreads();
#pragma unroll
    for (int c = 0; c < 2; ++c) {
      bf16x8 af[4], bfr[4];
#pragma unroll
      for (int mi = 0; mi < 4; ++mi)
        af[mi] = __builtin_bit_cast(bf16x8,
            *(const u16x8*)&As[c * 4096 + (wm * 64 + mi * 16 + lr) * 32 + quad * 8]);
#pragma unroll
      for (int ni = 0; ni < 4; ++ni)
        bfr[ni] = __builtin_bit_cast(bf16x8,
            *(const u16x8*)&Bs[c * 4096 + (wn * 64 + ni * 16 + lr) * 32 + quad * 8]);
#pragma unroll
      for (int mi = 0; mi < 4; ++mi)
#pragma unroll
        for (int ni = 0; ni < 4; ++ni)
          acc[mi][ni] = __builtin_amdgcn_mfma_f32_16x16x32_bf16(af[mi], bfr[ni], acc[mi][ni], 0, 0, 0);
    }
  }

  if (last) {
    float* Ob = outf + (size_t)bp * (F_ * N_);
#pragma unroll
    for (int mi = 0; mi < 4; ++mi) {
      int fbase = m0 + wm * 64 + mi * 16 + quad * 4;
#pragma unroll
      for (int ni = 0; ni < 4; ++ni) {
        int n = n0 + wn * 64 + ni * 16 + lr;
#pragma unroll
        for (int r = 0; r < 4; ++r) {
          float v = acc[mi][ni][r] + bias[fbase + r];
          Ob[(size_t)(fbase + r) * N_ + n] = v >= 0.f ? v : 0.01f * v;
        }
      }
    }
  } else {
    ushort_t* Ob = outb + (size_t)bp * (F_ * N_);
    float iv[4];
#pragma unroll
    for (int ni = 0; ni < 4; ++ni)
      iv[ni] = 1.0f / sumb[(size_t)bp * N_ + n0 + wn * 64 + ni * 16 + lr];
#pragma unroll
    for (int mi = 0; mi < 4; ++mi) {
      int fbase = m0 + wm * 64 + mi * 16 + quad * 4;
#pragma unroll
      for (int ni = 0; ni < 4; ++ni) {
        int n = n0 + wn * 64 + ni * 16 + lr;
#pragma unroll
        for (int r = 0; r < 4; ++r)
          Ob[(size_t)(fbase + r) * N_ + n] = f2bf(acc[mi][ni][r] * iv[ni]);
      }
    }
  }
}

// ---------------------------------------------------------------------------
// Fused persistent kernel: 512 blocks (2/CU guaranteed: LDS 38.4KB, VGPR<=256),
// phases separated by device-scope grid barriers.
__global__ __launch_bounds__(256, 2) void k_fused(
    const float* __restrict__ x, const float* __restrict__ mixer,
    const float* __restrict__ weight, const float* __restrict__ wb,
    const float* __restrict__ fw, const float* __restrict__ bias,
    const float* __restrict__ S, float* __restrict__ e1, float* __restrict__ e2,
    float* __restrict__ sumb, ushort_t* __restrict__ fwbf,
    ushort_t* __restrict__ xT, ushort_t* __restrict__ expT,
    ushort_t* __restrict__ sA, ushort_t* __restrict__ sB,
    float* __restrict__ out, unsigned* __restrict__ bar) {
  __shared__ __align__(16) char smem[38400];
  int L = blockIdx.x;

  // P1: prep (1664 jobs)
  for (int q = 0; q < 4; ++q) {
    int job = L + NBLK * q;
    if (job < 128) prep_e(job, x, mixer, weight, wb, e1, e2, smem);
    else if (job < 1152) prep_cast(job - 128, fw, fwbf);
    else if (job < 1664) prep_xT(job - 1152, x, xT, smem);
  }
  gridbar(bar, 1 * NBLK);

  // P2: attention — 4 jobs per block sharing one S tile (p = 0..3)
  {
    int b = L >> 6, i0 = ((L >> 2) & 15) * 64, jt = L & 3;
    for (int p = 0; p < 4; ++p)
      att_body(b * 4 + p, i0, jt, e1, e2, S, expT, sumb, smem);
  }
  gridbar(bar, 2 * NBLK);

  // P3..P6: Horner chain
  // s3' = (fw3*x).inv ; s2' = (s3'*E^T + fw2*x).inv ;
  // s1' = (s2'*E^T + fw1*x).inv ; out = lrelu(s1'*E^T + fw0*x + bias)
  gemm_body(L, sA, expT, fwbf, xT, bias, sumb, sA, out, 3, 0, 0, smem);
  gridbar(bar, 3 * NBLK);
  gemm_body(L, sA, expT, fwbf, xT, bias, sumb, sB, out, 2, 1, 0, smem);
  gridbar(bar, 4 * NBLK);
  gemm_body(L, sB, expT, fwbf, xT, bias, sumb, sA, out, 1, 1, 0, smem);
  gridbar(bar, 5 * NBLK);
  gemm_body(L, sA, expT, fwbf, xT, bias, sumb, nullptr, out, 0, 1, 1, smem);
}

// ---------------------------------------------------------------------------
extern "C" void kernel_launch(void* const* d_in, const int* in_sizes, int n_in,
                              void* d_out, int out_size, void* d_ws, size_t ws_size,
                              hipStream_t stream) {
  const float* x = (const float*)d_in[0];
  const float* mixer = (const float*)d_in[1];
  const float* weight = (const float*)d_in[2];
  const float* wb = (const float*)d_in[3];
  const float* fw = (const float*)d_in[4];
  const float* bias = (const float*)d_in[5];
  const float* S = (const float*)d_in[6];
  float* out = (float*)d_out;

  char* ws = (char*)d_ws;
  size_t off = 0;
  auto take = [&](size_t bytes) -> char* {
    char* p = ws + off;
    off = (off + bytes + 255) & ~(size_t)255;
    return p;
  };
  unsigned* bar = (unsigned*)take(256);
  float* e1 = (float*)take((size_t)B_ * P_ * N_ * 4);
  float* e2 = (float*)take((size_t)B_ * P_ * N_ * 4);
  float* sumb = (float*)take((size_t)B_ * P_ * N_ * 4);
  ushort_t* fwbf = (ushort_t*)take((size_t)P_ * F_ * KHOP * G_ * 2);
  ushort_t* xT = (ushort_t*)take((size_t)B_ * N_ * G_ * 2);
  ushort_t* expT = (ushort_t*)take((size_t)B_ * P_ * N_ * N_ * 2);
  ushort_t* sA = (ushort_t*)take((size_t)B_ * P_ * F_ * N_ * 2);
  ushort_t* sB = (ushort_t*)take((size_t)B_ * P_ * F_ * N_ * 2);

  hipMemsetAsync(bar, 0, 256, stream);
  hipMemsetAsync(sumb, 0, (size_t)B_ * P_ * N_ * 4, stream);
  k_fused<<<NBLK, 256, 0, stream>>>(x, mixer, weight, wb, fw, bias, S, e1, e2,
                                    sumb, fwbf, xT, expT, sA, sB, out, bar);
}

// Round 9
// 506.687 us; speedup vs baseline: 1.4685x; 1.4685x over previous
//
#include <hip/hip_runtime.h>
#include <hip/hip_bf16.h>

#define B_ 8
#define G_ 256
#define N_ 1024
#define P_ 4
#define F_ 256
#define KHOP 4
#define KG_ 1024   // KHOP*G_

typedef unsigned short ushort_t;
typedef __bf16 bf16x8 __attribute__((ext_vector_type(8)));
typedef unsigned short u16x8 __attribute__((ext_vector_type(8)));
typedef float f32x4 __attribute__((ext_vector_type(4)));

__device__ __forceinline__ unsigned short f2bf(float f) {
  union { float fl; unsigned int i; } v; v.fl = f;
  return (unsigned short)((v.i + 0x7fffu + ((v.i >> 16) & 1u)) >> 16);
}

__device__ __forceinline__ void gload_lds16(const ushort_t* g, ushort_t* l) {
  __builtin_amdgcn_global_load_lds(
      (const __attribute__((address_space(1))) void*)g,
      (__attribute__((address_space(3))) void*)l, 16, 0, 0);
}

// ---------------------------------------------------------------------------
// K-PREP: one kernel, block-range partitioned.
//   [0,128):    e1/e2 (recomputes w1/w2 in LDS per block - trivial)
//   [128,1152): filterWeight fp32->bf16
//   [1152,1664): xT[b][n][g] = bf16(x[b][g][n])
//   [1664,1792): zero sumb (+ att done-counter)
__global__ __launch_bounds__(256) void k_prep(
    const float* __restrict__ x, const float* __restrict__ mixer,
    const float* __restrict__ weight, const float* __restrict__ wb,
    const float* __restrict__ fw, float* __restrict__ e1, float* __restrict__ e2,
    ushort_t* __restrict__ fwbf, ushort_t* __restrict__ xT,
    float* __restrict__ sumb, unsigned* __restrict__ cnt) {
  int blk = blockIdx.x;
  int t = threadIdx.x;
  if (blk < 128) {
    __shared__ float s1[G_], s2[G_];
    __shared__ float cred[8];
    int bp = blk >> 2;
    int nc = blk & 3;
    int b = bp >> 2, p = bp & (P_ - 1);
    int n = nc * 256 + t;
    float acc1 = 0.f, acc2 = 0.f;
    const float* wp = weight + (size_t)p * F_ * G_ + t;
    const float* mp = mixer + p * 2 * F_;
    for (int f = 0; f < F_; ++f) {
      float wv = wp[(size_t)f * G_];
      acc1 = fmaf(mp[f], wv, acc1);
      acc2 = fmaf(mp[F_ + f], wv, acc2);
    }
    s1[t] = acc1;
    s2[t] = acc2;
    float c1p = mp[t] * wb[p * F_ + t];
    float c2p = mp[F_ + t] * wb[p * F_ + t];
#pragma unroll
    for (int mask = 1; mask < 64; mask <<= 1) {
      c1p += __shfl_xor(c1p, mask, 64);
      c2p += __shfl_xor(c2p, mask, 64);
    }
    if ((t & 63) == 0) {
      cred[t >> 6] = c1p;
      cred[4 + (t >> 6)] = c2p;
    }
    __syncthreads();
    float c1 = cred[0] + cred[1] + cred[2] + cred[3];
    float c2 = cred[4] + cred[5] + cred[6] + cred[7];
    const float* xb = x + (size_t)b * G_ * N_ + n;
    float a1 = 0.f, a2 = 0.f;
#pragma unroll 8
    for (int g = 0; g < G_; ++g) {
      float xv = xb[(size_t)g * N_];
      a1 = fmaf(s1[g], xv, a1);
      a2 = fmaf(s2[g], xv, a2);
    }
    e1[(size_t)bp * N_ + n] = c1 + a1;
    e2[(size_t)bp * N_ + n] = c2 + a2;
  } else if (blk < 128 + 1024) {
    int i = (blk - 128) * 1024 + t * 4;
    float4 v = *(const float4*)&fw[i];
    ushort4 o;
    o.x = f2bf(v.x); o.y = f2bf(v.y); o.z = f2bf(v.z); o.w = f2bf(v.w);
    *(ushort4*)&fwbf[i] = o;
  } else if (blk < 1152 + 512) {
    __shared__ ushort_t tile[64][66];
    int idx = blk - 1152;
    int n0 = (idx & 15) * 64;
    int g0 = ((idx >> 4) & 3) * 64;
    int b = idx >> 6;
    int rr = t >> 4, cc = (t & 15) * 4;
#pragma unroll
    for (int ps = 0; ps < 4; ++ps) {
      float4 v = *(const float4*)&x[((size_t)b * G_ + g0 + ps * 16 + rr) * N_ + n0 + cc];
      tile[ps * 16 + rr][cc] = f2bf(v.x);
      tile[ps * 16 + rr][cc + 1] = f2bf(v.y);
      tile[ps * 16 + rr][cc + 2] = f2bf(v.z);
      tile[ps * 16 + rr][cc + 3] = f2bf(v.w);
    }
    __syncthreads();
#pragma unroll
    for (int ps = 0; ps < 4; ++ps) {
      int nl = ps * 16 + rr;
      int gl = cc;
      ushort4 o;
      o.x = tile[gl][nl];
      o.y = tile[gl + 1][nl];
      o.z = tile[gl + 2][nl];
      o.w = tile[gl + 3][nl];
      *(ushort4*)&xT[((size_t)b * N_ + n0 + nl) * G_ + g0 + gl] = o;
    }
  } else {
    int i = (blk - 1664) * 256 + t;
    sumb[i] = 0.f;
    if (blk == 1664 && t == 0)
      __hip_atomic_store(cnt, 0u, __ATOMIC_RELAXED, __HIP_MEMORY_SCOPE_AGENT);
  }
}

// ---------------------------------------------------------------------------
// K-ATT (+embedded s3' GEMM): 2048 flat blocks, 4 blocks/CU (LDS 38.4KB).
// att job L: jt=L&3 (256-j-tile), itile=(L>>2)&15 (64-i-tile), bp=L>>6.
//   E[i,j] = m ? exp(lrelu(e1[j]+e2[i])) : 0 staged TRANSPOSED in LDS;
//   row sums atomically into sumb; tile dumped with 16B coalesced stores.
//   Then each block arrives at a device-scope done-counter (never waits).
// Blocks L<512 additionally compute one s3' tile: s3'[f][n] =
//   (sum_g fw3[f][g]*x[g][n]) / sumb[n], REUSING tile[] as GEMM LDS
//   (same __shared__ symbol -> address space preserved). They poll the
//   counter (relaxed + final acquire) only before the epilogue; deadlock-free
//   since waiters hold <=512 of 1024 resident slots and att jobs never wait.
__global__ __launch_bounds__(256, 4) void k_att(
    const float* __restrict__ e1, const float* __restrict__ e2,
    const float* __restrict__ S, ushort_t* __restrict__ expT,
    float* __restrict__ sumb, const ushort_t* __restrict__ fwbf,
    const ushort_t* __restrict__ xT, ushort_t* __restrict__ sA,
    unsigned* __restrict__ cnt) {
  __shared__ ushort_t tile[256][72];   // att: [j][i]; gemm3: As/Bs union
  __shared__ float se1[256];
  __shared__ float se2[64];
  int L = blockIdx.x;
  int bp = L >> 6;
  int i0 = ((L >> 2) & 15) * 64;
  int j0 = (L & 3) * 256;
  int b = bp >> 2;
  int t = threadIdx.x;
  int rr = t >> 4;
  int cc4 = t & 15;
  int cc = cc4 * 4;

  se1[t] = e1[(size_t)bp * N_ + j0 + t];
  if (t < 64) se2[t] = e2[(size_t)bp * N_ + i0 + t];
  __syncthreads();

  const float* Sb = S + (size_t)b * N_ * N_;
  float re2[4];
#pragma unroll
  for (int ps = 0; ps < 4; ++ps) re2[ps] = se2[ps * 16 + rr];
  float psum[4] = {0.f, 0.f, 0.f, 0.f};
#pragma unroll
  for (int js = 0; js < 4; ++js) {
    float4 e1q = *(float4*)&se1[js * 64 + cc];
    float e1v[4] = {e1q.x, e1q.y, e1q.z, e1q.w};
#pragma unroll
    for (int ps = 0; ps < 4; ++ps) {
      int il = ps * 16 + rr;
      float4 s4 = *(const float4*)&Sb[(size_t)(i0 + il) * N_ + j0 + js * 64 + cc];
      float sv[4] = {s4.x, s4.y, s4.z, s4.w};
#pragma unroll
      for (int s = 0; s < 4; ++s) {
        float v = e1v[s] + re2[ps];
        float l = v >= 0.f ? v : 0.2f * v;
        bool m = fabsf(sv[s]) > 1e-9f;
        float e = m ? __expf(l) : 0.f;
        psum[ps] += e;
        tile[js * 64 + cc + s][il] = f2bf(e);
      }
    }
  }
#pragma unroll
  for (int mask = 1; mask < 16; mask <<= 1) {
#pragma unroll
    for (int ps = 0; ps < 4; ++ps) psum[ps] += __shfl_xor(psum[ps], mask, 64);
  }
  if (cc4 == 0) {
#pragma unroll
    for (int ps = 0; ps < 4; ++ps)
      atomicAdd(&sumb[(size_t)bp * N_ + i0 + ps * 16 + rr], psum[ps]);
  }
  __syncthreads();
  {
    ushort_t* Tb = expT + (size_t)bp * N_ * N_;
    int jl0 = t >> 3;
    int ig = (t & 7) * 8;
#pragma unroll
    for (int pass = 0; pass < 8; ++pass) {
      int jl = pass * 32 + jl0;
      u16x8 v = *(const u16x8*)&tile[jl * 72 + ig - jl * 72 + jl * 72][0 + ig - ig + ig]; // placeholder avoided below
      (void)v;
      break;
    }
    // (real dump below — kept simple & identical to R7)
#pragma unroll
    for (int pass = 0; pass < 8; ++pass) {
      int jl = pass * 32 + jl0;
      u16x8 v = *(const u16x8*)&tile[jl][ig];
      *(u16x8*)&Tb[(size_t)(j0 + jl) * N_ + i0 + ig] = v;
    }
  }
  // ---- arrive (never wait) ----
  __syncthreads();
  if (t == 0) {
    __threadfence();
    __hip_atomic_fetch_add(cnt, 1u, __ATOMIC_RELEASE, __HIP_MEMORY_SCOPE_AGENT);
  }
  if (L >= 512) return;

  // ---- embedded s3' GEMM tile (K=256), LDS = tile[] reused ----
  {
    int bp2 = L >> 4;
    int p = bp2 & (P_ - 1), b2 = bp2 >> 2;
    int n0 = (L & 7) * 128, m0 = ((L >> 3) & 1) * 128;
    int lane = t & 63;
    int w = t >> 6;
    int wm = w >> 1, wn = w & 1;
    int lr = lane & 15, quad = lane >> 4;
    int rowL = t >> 2;
    int colL = (t & 3) * 8;
    int ldsoff = (t & ~63) * 8;
    ushort_t* lds = &tile[0][0];          // As: [0,8192); Bs: [8192,16384)

    const ushort_t* A2 = fwbf + (size_t)p * (F_ * KG_) + (size_t)(m0 + rowL) * KG_ +
                         3 * G_ + colL;
    const ushort_t* B2 = xT + (size_t)b2 * (N_ * G_) + (size_t)(n0 + rowL) * G_ + colL;

    f32x4 acc[4][4] = {};
    for (int gt = 0; gt < G_; gt += 64) {
      __syncthreads();
      gload_lds16(A2 + gt, &lds[ldsoff]);
      gload_lds16(A2 + (size_t)64 * KG_ + gt, &lds[2048 + ldsoff]);
      gload_lds16(A2 + gt + 32, &lds[4096 + ldsoff]);
      gload_lds16(A2 + (size_t)64 * KG_ + gt + 32, &lds[4096 + 2048 + ldsoff]);
      gload_lds16(B2 + gt, &lds[8192 + ldsoff]);
      gload_lds16(B2 + (size_t)64 * G_ + gt, &lds[8192 + 2048 + ldsoff]);
      gload_lds16(B2 + gt + 32, &lds[8192 + 4096 + ldsoff]);
      gload_lds16(B2 + (size_t)64 * G_ + gt + 32, &lds[8192 + 4096 + 2048 + ldsoff]);
      __syncthreads();
#pragma unroll
      for (int c = 0; c < 2; ++c) {
        bf16x8 af[4], bfr[4];
#pragma unroll
        for (int mi = 0; mi < 4; ++mi)
          af[mi] = __builtin_bit_cast(bf16x8,
              *(const u16x8*)&lds[c * 4096 + (wm * 64 + mi * 16 + lr) * 32 + quad * 8]);
#pragma unroll
        for (int ni = 0; ni < 4; ++ni)
          bfr[ni] = __builtin_bit_cast(bf16x8,
              *(const u16x8*)&lds[8192 + c * 4096 + (wn * 64 + ni * 16 + lr) * 32 + quad * 8]);
#pragma unroll
        for (int mi = 0; mi < 4; ++mi)
#pragma unroll
          for (int ni = 0; ni < 4; ++ni)
            acc[mi][ni] = __builtin_amdgcn_mfma_f32_16x16x32_bf16(af[mi], bfr[ni], acc[mi][ni], 0, 0, 0);
      }
    }
    // wait for all 2048 att arrivals (relaxed poll + one acquire)
    if (t == 0) {
      while (__hip_atomic_load(cnt, __ATOMIC_RELAXED, __HIP_MEMORY_SCOPE_AGENT) < 2048)
        __builtin_amdgcn_s_sleep(8);
      (void)__hip_atomic_load(cnt, __ATOMIC_ACQUIRE, __HIP_MEMORY_SCOPE_AGENT);
    }
    __syncthreads();
    ushort_t* Ob = sA + (size_t)bp2 * (F_ * N_);
    float iv[4];
#pragma unroll
    for (int ni = 0; ni < 4; ++ni)
      iv[ni] = 1.0f / sumb[(size_t)bp2 * N_ + n0 + wn * 64 + ni * 16 + lr];
#pragma unroll
    for (int mi = 0; mi < 4; ++mi) {
      int fbase = m0 + wm * 64 + mi * 16 + quad * 4;
#pragma unroll
      for (int ni = 0; ni < 4; ++ni) {
        int n = n0 + wn * 64 + ni * 16 + lr;
#pragma unroll
        for (int r = 0; r < 4; ++r)
          Ob[(size_t)(fbase + r) * N_ + n] = f2bf(acc[mi][ni][r] * iv[ni]);
      }
    }
  }
}

// ---------------------------------------------------------------------------
// Horner step GEMM (NT, MFMA bf16, 128x128 tile, 4 waves, BK=64, 2-barrier).
//   D[f,n] = sum_m Aprev[bp][f][m] * expT[bp][n][m]
//          + sum_g fwbf[p][f][kslice*256+g] * xT[b][n][g]
//   last: out_f32 = lrelu(D + bias[f]);  else out_bf16 = bf16(D / sumb[n]).
__global__ __launch_bounds__(256, 2) void gemm_step(
    const ushort_t* __restrict__ Aprev, const ushort_t* __restrict__ Bt,
    const ushort_t* __restrict__ fwbf, const ushort_t* __restrict__ xT,
    const float* __restrict__ bias, const float* __restrict__ sumb,
    ushort_t* __restrict__ outb, float* __restrict__ outf,
    int kslice, int last) {
  __shared__ ushort_t As[2][128 * 32];
  __shared__ ushort_t Bs[2][128 * 32];
  int bp = blockIdx.z;
  int p = bp & (P_ - 1), b = bp >> 2;
  int n0 = blockIdx.x * 128, m0 = blockIdx.y * 128;
  int t = threadIdx.x;
  int lane = t & 63;
  int w = t >> 6;
  int wm = w >> 1, wn = w & 1;
  int lr = lane & 15, quad = lane >> 4;
  int rowL = t >> 2;
  int colL = (t & 3) * 8;
  int ldsoff = (t & ~63) * 8;

  const ushort_t* A1 = Aprev + (size_t)bp * (F_ * N_) + (size_t)(m0 + rowL) * N_ + colL;
  const ushort_t* B1 = Bt + (size_t)bp * N_ * N_ + (size_t)(n0 + rowL) * N_ + colL;
  const ushort_t* A2 = fwbf + (size_t)p * (F_ * KG_) + (size_t)(m0 + rowL) * KG_ +
                       kslice * G_ + colL;
  const ushort_t* B2 = xT + (size_t)b * (N_ * G_) + (size_t)(n0 + rowL) * G_ + colL;

  f32x4 acc[4][4] = {};

  for (int kt = 0; kt < N_; kt += 64) {
    __syncthreads();
    gload_lds16(A1 + kt, &As[0][ldsoff]);
    gload_lds16(A1 + (size_t)64 * N_ + kt, &As[0][2048 + ldsoff]);
    gload_lds16(A1 + kt + 32, &As[1][ldsoff]);
    gload_lds16(A1 + (size_t)64 * N_ + kt + 32, &As[1][2048 + ldsoff]);
    gload_lds16(B1 + kt, &Bs[0][ldsoff]);
    gload_lds16(B1 + (size_t)64 * N_ + kt, &Bs[0][2048 + ldsoff]);
    gload_lds16(B1 + kt + 32, &Bs[1][ldsoff]);
    gload_lds16(B1 + (size_t)64 * N_ + kt + 32, &Bs[1][2048 + ldsoff]);
    __syncthreads();
#pragma unroll
    for (int c = 0; c < 2; ++c) {
      bf16x8 af[4], bfr[4];
#pragma unroll
      for (int mi = 0; mi < 4; ++mi)
        af[mi] = __builtin_bit_cast(bf16x8,
            *(const u16x8*)&As[c][(wm * 64 + mi * 16 + lr) * 32 + quad * 8]);
#pragma unroll
      for (int ni = 0; ni < 4; ++ni)
        bfr[ni] = __builtin_bit_cast(bf16x8,
            *(const u16x8*)&Bs[c][(wn * 64 + ni * 16 + lr) * 32 + quad * 8]);
#pragma unroll
      for (int mi = 0; mi < 4; ++mi)
#pragma unroll
        for (int ni = 0; ni < 4; ++ni)
          acc[mi][ni] = __builtin_amdgcn_mfma_f32_16x16x32_bf16(af[mi], bfr[ni], acc[mi][ni], 0, 0, 0);
    }
  }
  for (int gt = 0; gt < G_; gt += 64) {
    __syncthreads();
    gload_lds16(A2 + gt, &As[0][ldsoff]);
    gload_lds16(A2 + (size_t)64 * KG_ + gt, &As[0][2048 + ldsoff]);
    gload_lds16(A2 + gt + 32, &As[1][ldsoff]);
    gload_lds16(A2 + (size_t)64 * KG_ + gt + 32, &As[1][2048 + ldsoff]);
    gload_lds16(B2 + gt, &Bs[0][ldsoff]);
    gload_lds16(B2 + (size_t)64 * G_ + gt, &Bs[0][2048 + ldsoff]);
    gload_lds16(B2 + gt + 32, &Bs[1][ldsoff]);
    gload_lds16(B2 + (size_t)64 * G_ + gt + 32, &Bs[1][2048 + ldsoff]);
    __syncthreads();
#pragma unroll
    for (int c = 0; c < 2; ++c) {
      bf16x8 af[4], bfr[4];
#pragma unroll
      for (int mi = 0; mi < 4; ++mi)
        af[mi] = __builtin_bit_cast(bf16x8,
            *(const u16x8*)&As[c][(wm * 64 + mi * 16 + lr) * 32 + quad * 8]);
#pragma unroll
      for (int ni = 0; ni < 4; ++ni)
        bfr[ni] = __builtin_bit_cast(bf16x8,
            *(const u16x8*)&Bs[c][(wn * 64 + ni * 16 + lr) * 32 + quad * 8]);
#pragma unroll
      for (int mi = 0; mi < 4; ++mi)
#pragma unroll
        for (int ni = 0; ni < 4; ++ni)
          acc[mi][ni] = __builtin_amdgcn_mfma_f32_16x16x32_bf16(af[mi], bfr[ni], acc[mi][ni], 0, 0, 0);
    }
  }

  if (last) {
    float* Ob = outf + (size_t)bp * (F_ * N_);
#pragma unroll
    for (int mi = 0; mi < 4; ++mi) {
      int fbase = m0 + wm * 64 + mi * 16 + quad * 4;
#pragma unroll
      for (int ni = 0; ni < 4; ++ni) {
        int n = n0 + wn * 64 + ni * 16 + lr;
#pragma unroll
        for (int r = 0; r < 4; ++r) {
          float v = acc[mi][ni][r] + bias[fbase + r];
          Ob[(size_t)(fbase + r) * N_ + n] = v >= 0.f ? v : 0.01f * v;
        }
      }
    }
  } else {
    ushort_t* Ob = outb + (size_t)bp * (F_ * N_);
    float iv[4];
#pragma unroll
    for (int ni = 0; ni < 4; ++ni)
      iv[ni] = 1.0f / sumb[(size_t)bp * N_ + n0 + wn * 64 + ni * 16 + lr];
#pragma unroll
    for (int mi = 0; mi < 4; ++mi) {
      int fbase = m0 + wm * 64 + mi * 16 + quad * 4;
#pragma unroll
      for (int ni = 0; ni < 4; ++ni) {
        int n = n0 + wn * 64 + ni * 16 + lr;
#pragma unroll
        for (int r = 0; r < 4; ++r)
          Ob[(size_t)(fbase + r) * N_ + n] = f2bf(acc[mi][ni][r] * iv[ni]);
      }
    }
  }
}

// ---------------------------------------------------------------------------
extern "C" void kernel_launch(void* const* d_in, const int* in_sizes, int n_in,
                              void* d_out, int out_size, void* d_ws, size_t ws_size,
                              hipStream_t stream) {
  const float* x = (const float*)d_in[0];
  const float* mixer = (const float*)d_in[1];
  const float* weight = (const float*)d_in[2];
  const float* wb = (const float*)d_in[3];
  const float* fw = (const float*)d_in[4];
  const float* bias = (const float*)d_in[5];
  const float* S = (const float*)d_in[6];
  float* out = (float*)d_out;

  char* ws = (char*)d_ws;
  size_t off = 0;
  auto take = [&](size_t bytes) -> char* {
    char* p = ws + off;
    off = (off + bytes + 255) & ~(size_t)255;
    return p;
  };
  unsigned* cnt = (unsigned*)take(256);
  float* e1 = (float*)take((size_t)B_ * P_ * N_ * 4);
  float* e2 = (float*)take((size_t)B_ * P_ * N_ * 4);
  float* sumb = (float*)take((size_t)B_ * P_ * N_ * 4);
  ushort_t* fwbf = (ushort_t*)take((size_t)P_ * F_ * KHOP * G_ * 2);
  ushort_t* xT = (ushort_t*)take((size_t)B_ * N_ * G_ * 2);
  ushort_t* expT = (ushort_t*)take((size_t)B_ * P_ * N_ * N_ * 2);
  ushort_t* sA = (ushort_t*)take((size_t)B_ * P_ * F_ * N_ * 2);
  ushort_t* sB = (ushort_t*)take((size_t)B_ * P_ * F_ * N_ * 2);

  k_prep<<<1792, 256, 0, stream>>>(x, mixer, weight, wb, fw, e1, e2, fwbf, xT, sumb, cnt);
  // att (2048 jobs) + embedded s3' = (fw3*x).inv on blocks [0,512)
  k_att<<<2048, 256, 0, stream>>>(e1, e2, S, expT, sumb, fwbf, xT, sA, cnt);

  dim3 gg(8, 2, 32);
  // Horner: s2' = (s3'*E^T + fw2*x).inv ; s1' = (s2'*E^T + fw1*x).inv ;
  //         out = lrelu(s1'*E^T + fw0*x + bias)
  gemm_step<<<gg, 256, 0, stream>>>(sA, expT, fwbf, xT, bias, sumb, sB, nullptr, 2, 0);
  gemm_step<<<gg, 256, 0, stream>>>(sB, expT, fwbf, xT, bias, sumb, sA, nullptr, 1, 0);
  gemm_step<<<gg, 256, 0, stream>>>(sA, expT, fwbf, xT, bias, sumb, nullptr, out, 0, 1);
}